// Round 5
// baseline (65.149 us; speedup 1.0000x reference)
//
#include <hip/hip_runtime.h>

#define EPSF 1e-6f
#define L2E  1.44269504088896340736f   // log2(e)

typedef float v2f __attribute__((ext_vector_type(2)));

constexpr int NT      = 256;
constexpr int TILE    = 64;                  // q columns per block
constexpr int NPAIR   = TILE / 2;            // 32 column-pairs
constexpr int RPT     = 4;                   // z rows per thread
constexpr int ROWS_PB = NT * RPT;            // 1024 rows per block
constexpr int RBLK    = 16384 / ROWS_PB;     // 16
constexpr int CBLK    = 8192 / TILE;         // 128
constexpr int NB      = RBLK * CBLK;         // 2048 uniform blocks (8/CU)

// ---------------------------------------------------------------------------
__device__ __forceinline__ float block_reduce_sum(float v) {
#pragma unroll
    for (int off = 32; off > 0; off >>= 1) v += __shfl_down(v, off, 64);
    __shared__ float parts[4];
    const int t = threadIdx.x;
    if ((t & 63) == 0) parts[t >> 6] = v;
    __syncthreads();
    float r = 0.f;
    if (t == 0) r = parts[0] + parts[1] + parts[2] + parts[3];
    return r;
}

// ---------------------------------------------------------------------------
// Every block: [stage q-tile] -> [sparse slice] -> sync -> [dense 1024x64 tile]
// Dense math, log2 domain, two j-columns packed per v2f lane op:
//   a2 = {qn0,qn1} + zn;  a2 += (-2*zh_d)*{qh0_d,qh1_d}  (8 pk_fma)
//   term = ed_j * 2^(-sqrt(a2)),  zh = L2E*(z+eps), qh = L2E*q
// ---------------------------------------------------------------------------
__global__ __launch_bounds__(NT) void fused_kernel(
    const float* __restrict__ z, const float* __restrict__ q,
    const float* __restrict__ gamma, const float* __restrict__ delta,
    const float* __restrict__ w, const int* __restrict__ si,
    const int* __restrict__ sj, int nnz, float* __restrict__ partial)
{
    __shared__ __align__(16) float sqp[NPAIR][16]; // [rp][2*d+h] = qh pairs
    __shared__ __align__(8)  float sqn[NPAIR][2];  // {qn_j0, qn_j1}
    __shared__ __align__(8)  float sed[NPAIR][2];  // {ed_j0, ed_j1}

    const int t  = threadIdx.x;
    const int id = blockIdx.x;
    const int bi = id >> 7;          // id / CBLK, [0,16)
    const int j0 = (id & (CBLK - 1)) * TILE;

    // ---- stage q tile (64 threads; issue early) ----
    if (t < TILE) {
        const int j  = j0 + t;
        const int rp = t >> 1;
        const int h  = t & 1;
        const float4 c = *(const float4*)(q + (size_t)j * 8);
        const float4 d = *(const float4*)(q + (size_t)j * 8 + 4);
        const float h0 = L2E * c.x, h1 = L2E * c.y, h2 = L2E * c.z, h3 = L2E * c.w;
        const float h4 = L2E * d.x, h5 = L2E * d.y, h6 = L2E * d.z, h7 = L2E * d.w;
        sqp[rp][0  + h] = h0; sqp[rp][2  + h] = h1;
        sqp[rp][4  + h] = h2; sqp[rp][6  + h] = h3;
        sqp[rp][8  + h] = h4; sqp[rp][10 + h] = h5;
        sqp[rp][12 + h] = h6; sqp[rp][14 + h] = h7;
        sqn[rp][h] = h0*h0 + h1*h1 + h2*h2 + h3*h3
                   + h4*h4 + h5*h5 + h6*h6 + h7*h7;
        sed[rp][h] = __expf(delta[j] - EPSF);
    }

    // ---- sparse slice (before z-state is loaded: nothing fat live here) ----
    float sacc = 0.f;
    for (int k = id * NT + t; k < nnz; k += NB * NT) {
        const int i = si[k];
        const int j = sj[k];
        const float4 a = *(const float4*)(z + (size_t)i * 8);
        const float4 b = *(const float4*)(z + (size_t)i * 8 + 4);
        const float4 c = *(const float4*)(q + (size_t)j * 8);
        const float4 d = *(const float4*)(q + (size_t)j * 8 + 4);
        const float d0 = a.x - c.x + EPSF, d1 = a.y - c.y + EPSF;
        const float d2 = a.z - c.z + EPSF, d3 = a.w - c.w + EPSF;
        const float d4 = b.x - d.x + EPSF, d5 = b.y - d.y + EPSF;
        const float d6 = b.z - d.z + EPSF, d7 = b.w - d.w + EPSF;
        float s2 = d0 * d0;
        s2 = fmaf(d1, d1, s2); s2 = fmaf(d2, d2, s2); s2 = fmaf(d3, d3, s2);
        s2 = fmaf(d4, d4, s2); s2 = fmaf(d5, d5, s2); s2 = fmaf(d6, d6, s2);
        s2 = fmaf(d7, d7, s2);
        const float dist = __builtin_amdgcn_sqrtf(s2);
        sacc = fmaf(w[k], gamma[i] + delta[j] - dist, sacc);
    }
    __syncthreads();

    // ---- z-state (loaded AFTER sparse so it isn't live across it) ----
    float zm[RPT][8], zn[RPT], eg[RPT];
#pragma unroll
    for (int k = 0; k < RPT; ++k) {
        const int row = bi * ROWS_PB + k * NT + t;
        const float4 a = *(const float4*)(z + (size_t)row * 8);
        const float4 b = *(const float4*)(z + (size_t)row * 8 + 4);
        const float h0 = L2E * (a.x + EPSF), h1 = L2E * (a.y + EPSF);
        const float h2 = L2E * (a.z + EPSF), h3 = L2E * (a.w + EPSF);
        const float h4 = L2E * (b.x + EPSF), h5 = L2E * (b.y + EPSF);
        const float h6 = L2E * (b.z + EPSF), h7 = L2E * (b.w + EPSF);
        zn[k] = h0*h0 + h1*h1 + h2*h2 + h3*h3 + h4*h4 + h5*h5 + h6*h6 + h7*h7;
        zm[k][0] = -2.f * h0; zm[k][1] = -2.f * h1;
        zm[k][2] = -2.f * h2; zm[k][3] = -2.f * h3;
        zm[k][4] = -2.f * h4; zm[k][5] = -2.f * h5;
        zm[k][6] = -2.f * h6; zm[k][7] = -2.f * h7;
        eg[k] = __expf(gamma[row]);
    }

    // ---- dense tile ----
    v2f acc2[RPT] = {{0.f, 0.f}, {0.f, 0.f}, {0.f, 0.f}, {0.f, 0.f}};
#pragma unroll 2
    for (int rp = 0; rp < NPAIR; ++rp) {
        const float4 p0 = *(const float4*)&sqp[rp][0];   // dims 0,1
        const float4 p1 = *(const float4*)&sqp[rp][4];   // dims 2,3
        const float4 p2 = *(const float4*)&sqp[rp][8];   // dims 4,5
        const float4 p3 = *(const float4*)&sqp[rp][12];  // dims 6,7
        const v2f qn = *(const v2f*)sqn[rp];
        const v2f ed = *(const v2f*)sed[rp];
#pragma unroll
        for (int k = 0; k < RPT; ++k) {
            v2f a2 = qn + (v2f){zn[k], zn[k]};
            a2 = __builtin_elementwise_fma((v2f){zm[k][0], zm[k][0]}, (v2f){p0.x, p0.y}, a2);
            a2 = __builtin_elementwise_fma((v2f){zm[k][1], zm[k][1]}, (v2f){p0.z, p0.w}, a2);
            a2 = __builtin_elementwise_fma((v2f){zm[k][2], zm[k][2]}, (v2f){p1.x, p1.y}, a2);
            a2 = __builtin_elementwise_fma((v2f){zm[k][3], zm[k][3]}, (v2f){p1.z, p1.w}, a2);
            a2 = __builtin_elementwise_fma((v2f){zm[k][4], zm[k][4]}, (v2f){p2.x, p2.y}, a2);
            a2 = __builtin_elementwise_fma((v2f){zm[k][5], zm[k][5]}, (v2f){p2.z, p2.w}, a2);
            a2 = __builtin_elementwise_fma((v2f){zm[k][6], zm[k][6]}, (v2f){p3.x, p3.y}, a2);
            a2 = __builtin_elementwise_fma((v2f){zm[k][7], zm[k][7]}, (v2f){p3.z, p3.w}, a2);
            const float s0 = __builtin_amdgcn_sqrtf(fmaxf(a2.x, 0.f));
            const float s1 = __builtin_amdgcn_sqrtf(fmaxf(a2.y, 0.f));
            const v2f e2 = {__builtin_amdgcn_exp2f(-s0), __builtin_amdgcn_exp2f(-s1)};
            acc2[k] = __builtin_elementwise_fma(ed, e2, acc2[k]);
        }
    }

    float s = sacc;
#pragma unroll
    for (int k = 0; k < RPT; ++k) s = fmaf(-eg[k], acc2[k].x + acc2[k].y, s);
    const float v = block_reduce_sum(s);
    if (t == 0) partial[id] = v;
}

// ---------------------------------------------------------------------------
__global__ __launch_bounds__(256) void reduce_kernel(
    const float* __restrict__ partial, int n, float* __restrict__ out)
{
    float v = 0.f;
    for (int k = threadIdx.x; k < n; k += 256) v += partial[k];
    v = block_reduce_sum(v);
    if (threadIdx.x == 0) out[0] = v;
}

// ---------------------------------------------------------------------------
extern "C" void kernel_launch(void* const* d_in, const int* in_sizes, int n_in,
                              void* d_out, int out_size, void* d_ws, size_t ws_size,
                              hipStream_t stream) {
    const float* z     = (const float*)d_in[0];   // [16384, 8]
    const float* q     = (const float*)d_in[1];   // [8192, 8]
    const float* gamma = (const float*)d_in[2];   // [16384]
    const float* delta = (const float*)d_in[3];   // [8192]
    const float* w     = (const float*)d_in[4];   // [nnz]
    const int*   si    = (const int*)d_in[5];     // [nnz]
    const int*   sj    = (const int*)d_in[6];     // [nnz]
    const int    nnz   = in_sizes[4];

    float* out = (float*)d_out;
    float* ws  = (float*)d_ws;

    fused_kernel<<<NB, NT, 0, stream>>>(z, q, gamma, delta, w, si, sj, nnz, ws);
    reduce_kernel<<<1, 256, 0, stream>>>(ws, NB, out);
}

// Round 6
// 55.002 us; speedup vs baseline: 1.1845x; 1.1845x over previous
//
#include <hip/hip_runtime.h>

#define EPSF 1e-6f
#define L2E  1.44269504088896340736f   // log2(e)

using bf16x8 = __attribute__((ext_vector_type(8))) short;  // 8 bf16 (4 VGPRs)
using f32x4  = __attribute__((ext_vector_type(4))) float;

constexpr int NT   = 256;
constexpr int JC   = 512;               // q columns per block (chunk)
constexpr int NJC  = 8192 / JC;         // 16 chunks
constexpr int RPAN = 64;                // z rows per block (4 waves x 16)
constexpr int NRP  = 16384 / RPAN;      // 256 row panels
constexpr int NB   = NRP * NJC;         // 4096 blocks
constexpr int JT   = JC / 16;           // 32 j-tiles per chunk

// RNE float -> bf16 (as short), and back
__device__ __forceinline__ short f2bf(float f) {
    union { float f; unsigned u; } c{f};
    return (short)((c.u + 0x7fffu + ((c.u >> 16) & 1u)) >> 16);
}
__device__ __forceinline__ float bf2f(short s) {
    union { unsigned u; float f; } c{((unsigned)(unsigned short)s) << 16};
    return c.f;
}

// ---------------------------------------------------------------------------
__device__ __forceinline__ float block_reduce_sum(float v) {
#pragma unroll
    for (int off = 32; off > 0; off >>= 1) v += __shfl_down(v, off, 64);
    __shared__ float parts[4];
    const int t = threadIdx.x;
    if ((t & 63) == 0) parts[t >> 6] = v;
    __syncthreads();
    float r = 0.f;
    if (t == 0) r = parts[0] + parts[1] + parts[2] + parts[3];
    return r;
}

// ---------------------------------------------------------------------------
// Block: stage {bf16 z-panel rows, zn, exp(gamma)} + {bf16 q-chunk, qn, exp(delta-eps)}
// -> sparse slice -> sync -> per-wave MFMA over 32 j-tiles of a 16-row tile.
// Dense math: zh = bf16(L2E*(z+eps)), qh = bf16(L2E*q); S = zh.qh^T via MFMA;
//   a2 = zn + qn - 2S = L2E^2 * d2;  term = ed * 2^(-sqrt(a2)); weight eg at end.
// ---------------------------------------------------------------------------
__global__ __launch_bounds__(NT) void fused_kernel(
    const float* __restrict__ z, const float* __restrict__ q,
    const float* __restrict__ gamma, const float* __restrict__ delta,
    const float* __restrict__ w, const int* __restrict__ si,
    const int* __restrict__ sj, int nnz, float* __restrict__ partial)
{
    __shared__ short sza[RPAN * 8];   // bf16 z-panel
    __shared__ float szn[RPAN], seg[RPAN];
    __shared__ short sqb[JC * 8];     // bf16 q-chunk
    __shared__ float sqn[JC], sed[JC];

    const int t    = threadIdx.x;
    const int id   = blockIdx.x;
    const int jc   = id & (NJC - 1);
    const int rpan = id >> 4;
    const int c0   = jc * JC;

    // ---- stage z-panel (64 rows) ----
    if (t < RPAN) {
        const int row = rpan * RPAN + t;
        const float4 a = *(const float4*)(z + (size_t)row * 8);
        const float4 b = *(const float4*)(z + (size_t)row * 8 + 4);
        const float h[8] = {L2E * (a.x + EPSF), L2E * (a.y + EPSF),
                            L2E * (a.z + EPSF), L2E * (a.w + EPSF),
                            L2E * (b.x + EPSF), L2E * (b.y + EPSF),
                            L2E * (b.z + EPSF), L2E * (b.w + EPSF)};
        bf16x8 p;
        float zn = 0.f;
#pragma unroll
        for (int d = 0; d < 8; ++d) {
            const short s = f2bf(h[d]);
            p[d] = s;
            const float r = bf2f(s);
            zn = fmaf(r, r, zn);
        }
        *(bf16x8*)&sza[t * 8] = p;
        szn[t] = zn;
        seg[t] = __expf(gamma[row]);
    }

    // ---- stage q-chunk (512 cols, 2 per thread) ----
#pragma unroll
    for (int c = t; c < JC; c += NT) {
        const int C = c0 + c;
        const float4 a = *(const float4*)(q + (size_t)C * 8);
        const float4 b = *(const float4*)(q + (size_t)C * 8 + 4);
        const float h[8] = {L2E * a.x, L2E * a.y, L2E * a.z, L2E * a.w,
                            L2E * b.x, L2E * b.y, L2E * b.z, L2E * b.w};
        bf16x8 p;
        float qn = 0.f;
#pragma unroll
        for (int d = 0; d < 8; ++d) {
            const short s = f2bf(h[d]);
            p[d] = s;
            const float r = bf2f(s);
            qn = fmaf(r, r, qn);
        }
        *(bf16x8*)&sqb[c * 8] = p;
        sqn[c] = qn;
        sed[c] = __expf(delta[C] - EPSF);
    }

    // ---- sparse slice (exact fp32; nothing fat live across it) ----
    float sacc = 0.f;
    for (int k = id * NT + t; k < nnz; k += NB * NT) {
        const int i = si[k];
        const int j = sj[k];
        const float4 a = *(const float4*)(z + (size_t)i * 8);
        const float4 b = *(const float4*)(z + (size_t)i * 8 + 4);
        const float4 c = *(const float4*)(q + (size_t)j * 8);
        const float4 d = *(const float4*)(q + (size_t)j * 8 + 4);
        const float d0 = a.x - c.x + EPSF, d1 = a.y - c.y + EPSF;
        const float d2 = a.z - c.z + EPSF, d3 = a.w - c.w + EPSF;
        const float d4 = b.x - d.x + EPSF, d5 = b.y - d.y + EPSF;
        const float d6 = b.z - d.z + EPSF, d7 = b.w - d.w + EPSF;
        float s2 = d0 * d0;
        s2 = fmaf(d1, d1, s2); s2 = fmaf(d2, d2, s2); s2 = fmaf(d3, d3, s2);
        s2 = fmaf(d4, d4, s2); s2 = fmaf(d5, d5, s2); s2 = fmaf(d6, d6, s2);
        s2 = fmaf(d7, d7, s2);
        const float dist = __builtin_amdgcn_sqrtf(s2);
        sacc = fmaf(w[k], gamma[i] + delta[j] - dist, sacc);
    }
    __syncthreads();

    // ---- per-wave MFMA setup ----
    const int wv   = t >> 6;          // wave id (owns rows wv*16 .. wv*16+15)
    const int lane = t & 63;
    const int g    = lane >> 4;       // k-block / row-group
    const int li   = lane & 15;

    const bf16x8 zero8 = {0, 0, 0, 0, 0, 0, 0, 0};
    // A frag: lanes 0-15 carry k=0..7 (real), other k-blocks zero-padded
    const bf16x8 afrag = (g == 0) ? *(const bf16x8*)&sza[(wv * 16 + li) * 8] : zero8;

    float znr[4], egr[4];
#pragma unroll
    for (int r = 0; r < 4; ++r) {
        const int rr = wv * 16 + g * 4 + r;   // C/D row = (lane>>4)*4 + reg
        znr[r] = szn[rr];
        egr[r] = seg[rr];
    }

    // ---- j-loop: one MFMA + tiny epilogue per 16x16 tile ----
    f32x4 acc = {0.f, 0.f, 0.f, 0.f};
#pragma unroll 2
    for (int jt = 0; jt < JT; ++jt) {
        const int cb = jt * 16;
        const bf16x8 bfrag = (g == 0) ? *(const bf16x8*)&sqb[(cb + li) * 8] : zero8;
        const float qn_l = sqn[cb + li];     // C/D col = lane&15
        const float ed_l = sed[cb + li];
        const f32x4 s = __builtin_amdgcn_mfma_f32_16x16x32_bf16(
            afrag, bfrag, (f32x4){0.f, 0.f, 0.f, 0.f}, 0, 0, 0);
#pragma unroll
        for (int r = 0; r < 4; ++r) {
            float d2 = fmaf(s[r], -2.f, znr[r] + qn_l);
            d2 = fmaxf(d2, 0.f);
            const float st = __builtin_amdgcn_sqrtf(d2);      // = L2E * dist
            acc[r] = fmaf(ed_l, __builtin_amdgcn_exp2f(-st), acc[r]);
        }
    }

    float v = sacc;
#pragma unroll
    for (int r = 0; r < 4; ++r) v = fmaf(-egr[r], acc[r], v);
    v = block_reduce_sum(v);
    if (t == 0) partial[id] = v;
}

// ---------------------------------------------------------------------------
__global__ __launch_bounds__(256) void reduce_kernel(
    const float* __restrict__ partial, int n, float* __restrict__ out)
{
    float v = 0.f;
    for (int k = threadIdx.x; k < n; k += 256) v += partial[k];
    v = block_reduce_sum(v);
    if (threadIdx.x == 0) out[0] = v;
}

// ---------------------------------------------------------------------------
extern "C" void kernel_launch(void* const* d_in, const int* in_sizes, int n_in,
                              void* d_out, int out_size, void* d_ws, size_t ws_size,
                              hipStream_t stream) {
    const float* z     = (const float*)d_in[0];   // [16384, 8]
    const float* q     = (const float*)d_in[1];   // [8192, 8]
    const float* gamma = (const float*)d_in[2];   // [16384]
    const float* delta = (const float*)d_in[3];   // [8192]
    const float* w     = (const float*)d_in[4];   // [nnz]
    const int*   si    = (const int*)d_in[5];     // [nnz]
    const int*   sj    = (const int*)d_in[6];     // [nnz]
    const int    nnz   = in_sizes[4];

    float* out = (float*)d_out;
    float* ws  = (float*)d_ws;

    fused_kernel<<<NB, NT, 0, stream>>>(z, q, gamma, delta, w, si, sj, nnz, ws);
    reduce_kernel<<<1, 256, 0, stream>>>(ws, NB, out);
}

// Round 7
// 51.758 us; speedup vs baseline: 1.2587x; 1.0627x over previous
//
#include <hip/hip_runtime.h>

#define EPSF 1e-6f
#define L2E  1.44269504088896340736f   // log2(e)

using bf16x8 = __attribute__((ext_vector_type(8))) short;  // 8 bf16 (4 VGPRs)
using f32x16 = __attribute__((ext_vector_type(16))) float;

constexpr int NT   = 256;
constexpr int JC   = 256;               // q columns per block
constexpr int NJC  = 8192 / JC;         // 32 chunks
constexpr int RPAN = 128;               // z rows per block (4 waves x 32)
constexpr int NRP  = 16384 / RPAN;      // 128 row panels
constexpr int NB   = NRP * NJC;         // 4096 blocks
constexpr int JT   = JC / 32;           // 8 j-tiles per chunk

// RNE float -> bf16 (as short), and back
__device__ __forceinline__ short f2bf(float f) {
    union { float f; unsigned u; } c{f};
    return (short)((c.u + 0x7fffu + ((c.u >> 16) & 1u)) >> 16);
}
__device__ __forceinline__ float bf2f(short s) {
    union { unsigned u; float f; } c{((unsigned)(unsigned short)s) << 16};
    return c.f;
}

// ---------------------------------------------------------------------------
__device__ __forceinline__ float block_reduce_sum(float v) {
#pragma unroll
    for (int off = 32; off > 0; off >>= 1) v += __shfl_down(v, off, 64);
    __shared__ float parts[4];
    const int t = threadIdx.x;
    if ((t & 63) == 0) parts[t >> 6] = v;
    __syncthreads();
    float r = 0.f;
    if (t == 0) r = parts[0] + parts[1] + parts[2] + parts[3];
    return r;
}

// ---------------------------------------------------------------------------
// Dense: K=10 augmented MFMA emits d2 directly.
//   A row i = [zh_0..zh_7, zn_i, 1, 0...]  (zh = bf16(L2E*(z+eps)), zn=|zh|^2)
//   B col j = [-2*qh_0..-2*qh_7, 1, qn_j, 0...] (qh = bf16(L2E*q), qn=|qh|^2)
//   D = zn + qn - 2*zh.qh = L2E^2 * d2;  term = ed_j * 2^(-sqrt(D))
// 32x32x16 MFMA: A lane(row=l&31, kg=l>>5) k=8kg..8kg+7; same for B cols.
// C/D: col=lane&31, row=(reg&3)+8*(reg>>2)+4*(lane>>5).
// ---------------------------------------------------------------------------
__global__ __launch_bounds__(NT) void fused_kernel(
    const float* __restrict__ z, const float* __restrict__ q,
    const float* __restrict__ gamma, const float* __restrict__ delta,
    const float* __restrict__ w, const int* __restrict__ si,
    const int* __restrict__ sj, int nnz, float* __restrict__ partial)
{
    __shared__ short sza[RPAN * 16];   // 4KB  A-side rows (16 bf16 each)
    __shared__ float seg[RPAN];        // 512B exp(gamma)
    __shared__ short sqb[JC * 16];     // 8KB  B-side cols (16 bf16 each)
    __shared__ float sed[JC];          // 1KB  exp(delta - eps)

    const int t    = threadIdx.x;
    const int id   = blockIdx.x;
    const int jc   = id & (NJC - 1);
    const int rpan = id >> 5;          // id / NJC
    const int c0   = jc * JC;

    // ---- stage z-panel (128 rows; threads 0..127) ----
    if (t < RPAN) {
        const int row = rpan * RPAN + t;
        const float4 a = *(const float4*)(z + (size_t)row * 8);
        const float4 b = *(const float4*)(z + (size_t)row * 8 + 4);
        const float h[8] = {L2E * (a.x + EPSF), L2E * (a.y + EPSF),
                            L2E * (a.z + EPSF), L2E * (a.w + EPSF),
                            L2E * (b.x + EPSF), L2E * (b.y + EPSF),
                            L2E * (b.z + EPSF), L2E * (b.w + EPSF)};
        float zn = 0.f;
#pragma unroll
        for (int d = 0; d < 8; ++d) {
            const short s = f2bf(h[d]);
            sza[t * 16 + d] = s;
            const float r = bf2f(s);
            zn = fmaf(r, r, zn);
        }
        sza[t * 16 + 8] = f2bf(zn);
        sza[t * 16 + 9] = (short)0x3F80;   // 1.0 bf16
#pragma unroll
        for (int d = 10; d < 16; ++d) sza[t * 16 + d] = 0;
        seg[t] = __expf(gamma[row]);
    }

    // ---- stage q-chunk (256 cols; one per thread) ----
    {
        const int C = c0 + t;
        const float4 a = *(const float4*)(q + (size_t)C * 8);
        const float4 b = *(const float4*)(q + (size_t)C * 8 + 4);
        const float h[8] = {L2E * a.x, L2E * a.y, L2E * a.z, L2E * a.w,
                            L2E * b.x, L2E * b.y, L2E * b.z, L2E * b.w};
        float qn = 0.f;
#pragma unroll
        for (int d = 0; d < 8; ++d) {
            const short s = f2bf(h[d]);
            const float r = bf2f(s);
            qn = fmaf(r, r, qn);
            sqb[t * 16 + d] = f2bf(-2.f * r);  // exact: -2x is exponent shift
        }
        sqb[t * 16 + 8] = (short)0x3F80;       // 1.0 bf16
        sqb[t * 16 + 9] = f2bf(qn);
#pragma unroll
        for (int d = 10; d < 16; ++d) sqb[t * 16 + d] = 0;
        sed[t] = __expf(delta[C] - EPSF);
    }

    // ---- sparse slice (exact fp32; nothing fat live across it) ----
    float sacc = 0.f;
    for (int k = id * NT + t; k < nnz; k += NB * NT) {
        const int i = si[k];
        const int j = sj[k];
        const float4 a = *(const float4*)(z + (size_t)i * 8);
        const float4 b = *(const float4*)(z + (size_t)i * 8 + 4);
        const float4 c = *(const float4*)(q + (size_t)j * 8);
        const float4 d = *(const float4*)(q + (size_t)j * 8 + 4);
        const float d0 = a.x - c.x + EPSF, d1 = a.y - c.y + EPSF;
        const float d2 = a.z - c.z + EPSF, d3 = a.w - c.w + EPSF;
        const float d4 = b.x - d.x + EPSF, d5 = b.y - d.y + EPSF;
        const float d6 = b.z - d.z + EPSF, d7 = b.w - d.w + EPSF;
        float s2 = d0 * d0;
        s2 = fmaf(d1, d1, s2); s2 = fmaf(d2, d2, s2); s2 = fmaf(d3, d3, s2);
        s2 = fmaf(d4, d4, s2); s2 = fmaf(d5, d5, s2); s2 = fmaf(d6, d6, s2);
        s2 = fmaf(d7, d7, s2);
        const float dist = __builtin_amdgcn_sqrtf(s2);
        sacc = fmaf(w[k], gamma[i] + delta[j] - dist, sacc);
    }
    __syncthreads();

    // ---- per-wave MFMA over 8 j-tiles of a 32-row band ----
    const int wv   = t >> 6;
    const int lane = t & 63;
    const int li   = lane & 31;
    const int half = lane >> 5;

    const bf16x8 afrag = *(const bf16x8*)&sza[(wv * 32 + li) * 16 + half * 8];
    const short* bp    = &sqb[li * 16 + half * 8];
    const float* edp   = &sed[li];

    float acc[16];
#pragma unroll
    for (int r = 0; r < 16; ++r) acc[r] = 0.f;

#pragma unroll
    for (int jt = 0; jt < JT; ++jt) {
        const bf16x8 bfrag = *(const bf16x8*)(bp + jt * 32 * 16);
        const float  ed_l  = edp[jt * 32];
        f32x16 s = __builtin_amdgcn_mfma_f32_32x32x16_bf16(
            afrag, bfrag, (f32x16)(0.f), 0, 0, 0);
#pragma unroll
        for (int r = 0; r < 16; ++r) {
            const float d2 = fmaxf(s[r], 0.f);
            const float st = __builtin_amdgcn_sqrtf(d2);   // = L2E * dist
            acc[r] = fmaf(ed_l, __builtin_amdgcn_exp2f(-st), acc[r]);
        }
    }

    // weight by exp(gamma_row); row = wv*32 + 4*half + (reg&3) + 8*(reg>>2)
    float vv = 0.f;
#pragma unroll
    for (int r4 = 0; r4 < 4; ++r4)
#pragma unroll
        for (int r0 = 0; r0 < 4; ++r0)
            vv = fmaf(seg[wv * 32 + half * 4 + r0 + 8 * r4], acc[r4 * 4 + r0], vv);

    const float v = block_reduce_sum(sacc - vv);
    if (t == 0) partial[id] = v;
}

// ---------------------------------------------------------------------------
__global__ __launch_bounds__(256) void reduce_kernel(
    const float* __restrict__ partial, int n, float* __restrict__ out)
{
    float v = 0.f;
    for (int k = threadIdx.x; k < n; k += 256) v += partial[k];
    v = block_reduce_sum(v);
    if (threadIdx.x == 0) out[0] = v;
}

// ---------------------------------------------------------------------------
extern "C" void kernel_launch(void* const* d_in, const int* in_sizes, int n_in,
                              void* d_out, int out_size, void* d_ws, size_t ws_size,
                              hipStream_t stream) {
    const float* z     = (const float*)d_in[0];   // [16384, 8]
    const float* q     = (const float*)d_in[1];   // [8192, 8]
    const float* gamma = (const float*)d_in[2];   // [16384]
    const float* delta = (const float*)d_in[3];   // [8192]
    const float* w     = (const float*)d_in[4];   // [nnz]
    const int*   si    = (const int*)d_in[5];     // [nnz]
    const int*   sj    = (const int*)d_in[6];     // [nnz]
    const int    nnz   = in_sizes[4];

    float* out = (float*)d_out;
    float* ws  = (float*)d_ws;

    fused_kernel<<<NB, NT, 0, stream>>>(z, q, gamma, delta, w, si, sj, nnz, ws);
    reduce_kernel<<<1, 256, 0, stream>>>(ws, NB, out);
}